// Round 2
// baseline (191.915 us; speedup 1.0000x reference)
//
#include <hip/hip_runtime.h>

#define FEATS 64
#define HSZ   4096
#define ISZ   12480          // (FEATS+1)*FEATS*3
#define I4    (ISZ/4)        // 3120 float4
#define H4    (HSZ/4)        // 1024 float4

// workspace layout (float offsets)
#define X_OFF  0             // 12480
#define GI_OFF 12480         // 12288
#define GH_OFF 24768         // 12288

#define GI_RPB 8                      // rows per GI block (2 per wave)
#define GH_RPB 24                     // rows per GH block (6 per wave)
#define GI_NB  (3 * HSZ / GI_RPB)     // 1536
#define GH_NB  (3 * HSZ / GH_RPB)     // 512

// ---------------- A: fused GAT (matmuls + softmax + assemble x) -------------------
__global__ __launch_bounds__(1024)
void gat_all(const float* __restrict__ data,
             const float* __restrict__ fW, const float* __restrict__ fal,
             const float* __restrict__ fb,
             const float* __restrict__ tW, const float* __restrict__ tal,
             const float* __restrict__ tb,
             float* __restrict__ ws) {
    __shared__ float hf[64][64];
    __shared__ float ht[64][64];
    __shared__ float out0[2][64];
    int tid = threadIdx.x;

    // 8192 matmul outputs, 8 per thread; `which` is uniform per iteration
    for (int o = tid; o < 8192; o += 1024) {
        int which = o >> 12;
        int oo    = o & 4095;
        int v     = oo >> 6;          // node v+1 (row 0 of padded input is zero)
        int j     = oo & 63;
        float acc = 0.f;
        if (which == 0) {
            #pragma unroll 8
            for (int k = 0; k < 64; ++k) acc += data[v*64 + k] * fW[k*64 + j];
            hf[v][j] = acc;
        } else {
            #pragma unroll 8
            for (int k = 0; k < 64; ++k) acc += data[k*64 + v] * tW[k*64 + j];
            ht[v][j] = acc;
        }
    }
    __syncthreads();

    if (tid < 128) {
        int which = tid >> 6;
        int j     = tid & 63;
        const float* h = which ? &ht[0][0] : &hf[0][0];
        float al = which ? tal[j] : fal[j];
        // e[v] = leaky_relu(h[v]*al[j]); node 0: h=0 -> e=0 (ar drops out)
        float m = 0.f;
        for (int v = 0; v < 64; ++v) {
            float e = h[v*64 + j] * al;
            e = e > 0.f ? e : 0.2f * e;
            m = fmaxf(m, e);
        }
        float sum = expf(0.f - m);    // node-0 term (numerator contribution is 0)
        float num = 0.f;
        for (int v = 0; v < 64; ++v) {
            float hv = h[v*64 + j];
            float e  = hv * al;
            e = e > 0.f ? e : 0.2f * e;
            float a = expf(e - m);
            sum += a;
            num += a * hv;
        }
        out0[which][j] = num / sum;
    }
    __syncthreads();

    // x[(n*64+f)*3 + c]: c0 = data_r, c1 = feat_r + fb, c2 = time_r + tb
    for (int idx = tid; idx < ISZ; idx += 1024) {
        int c  = idx % 3;
        int nf = idx / 3;
        int n  = nf >> 6;
        int f  = nf & 63;
        float val;
        if (c == 0)      val = (n == 0) ? 0.f : data[(n-1)*64 + f];
        else if (c == 1) val = ((n == 0) ? out0[0][f] : hf[n-1][f]) + fb[f];
        else             val = ((n == 0) ? out0[1][f] : ht[n-1][f]) + tb[f];
        ws[X_OFF + idx] = val;
    }
}

// ---------------- B: the two big matvecs (memory-bound; 815 MB of weights) ---------
__device__ __forceinline__ float wave_reduce(float v) {
    #pragma unroll
    for (int off = 32; off > 0; off >>= 1) v += __shfl_down(v, off);
    return v;
}

__device__ __forceinline__ float fma4(float4 w, float4 v, float a) {
    return fmaf(w.x, v.x, fmaf(w.y, v.y, fmaf(w.z, v.z, fmaf(w.w, v.w, a))));
}

__global__ __launch_bounds__(256, 4)
void big_matvec(const float* __restrict__ W_ih,
                const float* __restrict__ W_hh,
                const float* __restrict__ h0,
                float* __restrict__ ws) {
    int b    = blockIdx.x;
    int wave = threadIdx.x >> 6;
    int lane = threadIdx.x & 63;

    if (b < GI_NB) {
        // 2 rows per wave, 49.9 KB each; x is L2-resident
        int r = b * GI_RPB + wave * 2;
        const float4* x4 = (const float4*)(ws + X_OFF);
        const float4* W0 = (const float4*)W_ih + (size_t)r * I4;
        const float4* W1 = W0 + I4;
        float a0 = 0.f, a1 = 0.f;
        int k = lane;
        #pragma unroll 4
        for (int i = 0; i < 48; ++i, k += 64) {
            float4 v = x4[k], w0 = W0[k], w1 = W1[k];
            a0 = fma4(w0, v, a0);
            a1 = fma4(w1, v, a1);
        }
        if (lane < 48) {                       // remainder: 3120 = 48*64 + 48
            int kk = 3072 + lane;
            float4 v = x4[kk], w0 = W0[kk], w1 = W1[kk];
            a0 = fma4(w0, v, a0);
            a1 = fma4(w1, v, a1);
        }
        a0 = wave_reduce(a0);
        a1 = wave_reduce(a1);
        if (lane == 0) {
            ws[GI_OFF + r]     = a0;
            ws[GI_OFF + r + 1] = a1;
        }
    } else {
        // 6 rows per wave in 3 ILP-pairs, 16 KB each; h0 is L2-resident
        int base = (b - GI_NB) * GH_RPB + wave * 6;
        const float4* h4 = (const float4*)h0;
        #pragma unroll
        for (int p = 0; p < 6; p += 2) {
            int r = base + p;
            const float4* W0 = (const float4*)W_hh + (size_t)r * H4;
            const float4* W1 = W0 + H4;
            float a0 = 0.f, a1 = 0.f;
            int k = lane;
            #pragma unroll 4
            for (int i = 0; i < 16; ++i, k += 64) {   // 1024 = 16*64 exactly
                float4 v = h4[k], w0 = W0[k], w1 = W1[k];
                a0 = fma4(w0, v, a0);
                a1 = fma4(w1, v, a1);
            }
            a0 = wave_reduce(a0);
            a1 = wave_reduce(a1);
            if (lane == 0) {
                ws[GH_OFF + r]     = a0;
                ws[GH_OFF + r + 1] = a1;
            }
        }
    }
}

// ---------------- C: GRU gate math + write both output copies ----------------------
__global__ void gru_combine(const float* __restrict__ h0,
                            const float* __restrict__ b_ih,
                            const float* __restrict__ b_hh,
                            const float* __restrict__ ws,
                            float* __restrict__ out) {
    int j = blockIdx.x * 256 + threadIdx.x;
    if (j >= HSZ) return;
    const float* gi = ws + GI_OFF;
    const float* gh = ws + GH_OFF;
    float ir  = gi[j]         + b_ih[j];
    float iz  = gi[HSZ + j]   + b_ih[HSZ + j];
    float in_ = gi[2*HSZ + j] + b_ih[2*HSZ + j];
    float hr  = gh[j]         + b_hh[j];
    float hz  = gh[HSZ + j]   + b_hh[HSZ + j];
    float hn  = gh[2*HSZ + j] + b_hh[2*HSZ + j];
    float r = 1.f / (1.f + expf(-(ir + hr)));
    float z = 1.f / (1.f + expf(-(iz + hz)));
    float n = tanhf(in_ + r * hn);
    float h = (1.f - z) * n + z * h0[j];
    out[j]       = h;
    out[HSZ + j] = h;
}

extern "C" void kernel_launch(void* const* d_in, const int* in_sizes, int n_in,
                              void* d_out, int out_size, void* d_ws, size_t ws_size,
                              hipStream_t stream) {
    const float* data    = (const float*)d_in[0];
    const float* hidden  = (const float*)d_in[1];
    const float* fgat_W  = (const float*)d_in[2];
    const float* fgat_al = (const float*)d_in[3];
    // d_in[4] = fgat_ar (unused: er[0] = h[0]*ar = 0 since padded row 0 is zero)
    const float* fgat_b  = (const float*)d_in[5];
    const float* tgat_W  = (const float*)d_in[6];
    const float* tgat_al = (const float*)d_in[7];
    // d_in[8] = tgat_ar (unused, same reason)
    const float* tgat_b  = (const float*)d_in[9];
    const float* W_ih    = (const float*)d_in[10];
    const float* W_hh    = (const float*)d_in[11];
    const float* b_ih    = (const float*)d_in[12];
    const float* b_hh    = (const float*)d_in[13];
    float* ws  = (float*)d_ws;
    float* out = (float*)d_out;

    gat_all<<<1, 1024, 0, stream>>>(data, fgat_W, fgat_al, fgat_b,
                                    tgat_W, tgat_al, tgat_b, ws);
    big_matvec<<<GI_NB + GH_NB, 256, 0, stream>>>(W_ih, W_hh, hidden, ws);
    gru_combine<<<(HSZ + 255) / 256, 256, 0, stream>>>(hidden, b_ih, b_hh, ws, out);
}

// Round 4
// 161.077 us; speedup vs baseline: 1.1915x; 1.1915x over previous
//
#include <hip/hip_runtime.h>

#define FEATS 64
#define HSZ   4096
#define ISZ   12480          // (FEATS+1)*FEATS*3
#define I4    (ISZ/4)        // 3120 float4
#define H4    (HSZ/4)        // 1024 float4

// workspace layout (float offsets)
#define X_OFF  0             // 12480
#define GI_OFF 12480         // 12288
#define GH_OFF 24768         // 12288
#define HF_OFF 37056         // 4096
#define HT_OFF 41152         // 4096

#define GI_RPB 8                      // rows per GI block (2 per wave)
#define GH_RPB 24                     // rows per GH block (6 per wave)
#define GI_NB  (3 * HSZ / GI_RPB)     // 1536
#define GH_NB  (3 * HSZ / GH_RPB)     // 512

typedef float f4 __attribute__((ext_vector_type(4)));   // native vec: NT-load OK

// ---------------- A1: the two 64x64 GAT matmuls (rows 1..64; padded row 0 = 0) -----
__global__ void gat_matmul(const float* __restrict__ data,
                           const float* __restrict__ fW,
                           const float* __restrict__ tW,
                           float* __restrict__ ws) {
    int idx   = blockIdx.x * 256 + threadIdx.x;   // 0..8191
    int which = idx >> 12;                        // 0: feat GAT, 1: time GAT
    int o     = idx & 4095;
    int v     = o >> 6;                           // node v+1
    int j     = o & 63;
    float acc = 0.f;
    if (which == 0) {
        #pragma unroll 8
        for (int k = 0; k < 64; ++k) acc += data[v*64 + k] * fW[k*64 + j];
    } else {
        #pragma unroll 8
        for (int k = 0; k < 64; ++k) acc += data[k*64 + v] * tW[k*64 + j];
    }
    ws[(which ? HT_OFF : HF_OFF) + o] = acc;
}

// ---------------- A2: softmax over the 65-node star + assemble GRU input x ----------
__global__ __launch_bounds__(512)
void gat_softmax_assemble(const float* __restrict__ data,
                          const float* __restrict__ fal,
                          const float* __restrict__ fb,
                          const float* __restrict__ tal,
                          const float* __restrict__ tb,
                          float* __restrict__ ws) {
    __shared__ float out0[2][64];
    int tid = threadIdx.x;
    if (tid < 128) {
        int which = tid >> 6;
        int j     = tid & 63;
        const float* h = ws + (which ? HT_OFF : HF_OFF);
        float al = which ? tal[j] : fal[j];
        // e[v] = leaky_relu(h[v]*al[j]); node 0: h=0 -> e=0 (ar drops out entirely)
        float m = 0.f;                 // includes node-0 term e=0
        for (int v = 0; v < 64; ++v) {
            float e = h[v*64 + j] * al;
            e = e > 0.f ? e : 0.2f * e;
            m = fmaxf(m, e);
        }
        float sum = __expf(0.f - m);   // node-0 term (zero numerator contribution)
        float num = 0.f;
        for (int v = 0; v < 64; ++v) {
            float hv = h[v*64 + j];
            float e  = hv * al;
            e = e > 0.f ? e : 0.2f * e;
            float a = __expf(e - m);
            sum += a;
            num += a * hv;
        }
        out0[which][j] = num / sum;
    }
    __syncthreads();
    // x[(n*64+f)*3 + c]: c0 = data_r, c1 = feat_r + fb, c2 = time_r + tb
    for (int idx = tid; idx < ISZ; idx += 512) {
        int c  = idx % 3;
        int nf = idx / 3;
        int n  = nf >> 6;
        int f  = nf & 63;
        float val;
        if (c == 0)      val = (n == 0) ? 0.f : data[(n-1)*64 + f];
        else if (c == 1) val = ((n == 0) ? out0[0][f] : ws[HF_OFF + (n-1)*64 + f]) + fb[f];
        else             val = ((n == 0) ? out0[1][f] : ws[HT_OFF + (n-1)*64 + f]) + tb[f];
        ws[X_OFF + idx] = val;
    }
}

// ---------------- B: the two big matvecs (memory-bound; 815 MB of weights) ---------
__device__ __forceinline__ float wave_reduce(float v) {
    #pragma unroll
    for (int off = 32; off > 0; off >>= 1) v += __shfl_down(v, off);
    return v;
}

__device__ __forceinline__ float fma4(f4 w, f4 v, float a) {
    return fmaf(w.x, v.x, fmaf(w.y, v.y, fmaf(w.z, v.z, fmaf(w.w, v.w, a))));
}

__device__ __forceinline__ f4 ntload(const f4* p) {
    return __builtin_nontemporal_load(p);   // weights are use-once: bypass L2 insert
}

__global__ __launch_bounds__(256, 4)
void big_matvec(const float* __restrict__ W_ih,
                const float* __restrict__ W_hh,
                const float* __restrict__ h0,
                float* __restrict__ ws) {
    int b    = blockIdx.x;
    int wave = threadIdx.x >> 6;
    int lane = threadIdx.x & 63;

    if (b < GI_NB) {
        // 2 rows per wave, 49.9 KB each; x stays L2-resident (cached loads)
        int r = b * GI_RPB + wave * 2;
        const f4* x4 = (const f4*)(ws + X_OFF);
        const f4* W0 = (const f4*)W_ih + (size_t)r * I4;
        const f4* W1 = W0 + I4;
        float a0 = 0.f, a1 = 0.f;
        int k = lane;
        #pragma unroll 8
        for (int i = 0; i < 48; ++i, k += 64) {
            f4 v  = x4[k];
            f4 w0 = ntload(W0 + k);
            f4 w1 = ntload(W1 + k);
            a0 = fma4(w0, v, a0);
            a1 = fma4(w1, v, a1);
        }
        if (lane < 48) {                       // remainder: 3120 = 48*64 + 48
            int kk = 3072 + lane;
            f4 v  = x4[kk];
            f4 w0 = ntload(W0 + kk);
            f4 w1 = ntload(W1 + kk);
            a0 = fma4(w0, v, a0);
            a1 = fma4(w1, v, a1);
        }
        a0 = wave_reduce(a0);
        a1 = wave_reduce(a1);
        if (lane == 0) {
            ws[GI_OFF + r]     = a0;
            ws[GI_OFF + r + 1] = a1;
        }
    } else {
        // 6 rows per wave in 3 ILP-pairs, 16 KB each; h0 is L2-resident
        int base = (b - GI_NB) * GH_RPB + wave * 6;
        const f4* h4 = (const f4*)h0;
        #pragma unroll
        for (int p = 0; p < 6; p += 2) {
            int r = base + p;
            const f4* W0 = (const f4*)W_hh + (size_t)r * H4;
            const f4* W1 = W0 + H4;
            float a0 = 0.f, a1 = 0.f;
            int k = lane;
            #pragma unroll 8
            for (int i = 0; i < 16; ++i, k += 64) {   // 1024 = 16*64 exactly
                f4 v  = h4[k];
                f4 w0 = ntload(W0 + k);
                f4 w1 = ntload(W1 + k);
                a0 = fma4(w0, v, a0);
                a1 = fma4(w1, v, a1);
            }
            a0 = wave_reduce(a0);
            a1 = wave_reduce(a1);
            if (lane == 0) {
                ws[GH_OFF + r]     = a0;
                ws[GH_OFF + r + 1] = a1;
            }
        }
    }
}

// ---------------- C: GRU gate math + write both output copies ----------------------
__global__ void gru_combine(const float* __restrict__ h0,
                            const float* __restrict__ b_ih,
                            const float* __restrict__ b_hh,
                            const float* __restrict__ ws,
                            float* __restrict__ out) {
    int j = blockIdx.x * 256 + threadIdx.x;
    if (j >= HSZ) return;
    const float* gi = ws + GI_OFF;
    const float* gh = ws + GH_OFF;
    float ir  = gi[j]         + b_ih[j];
    float iz  = gi[HSZ + j]   + b_ih[HSZ + j];
    float in_ = gi[2*HSZ + j] + b_ih[2*HSZ + j];
    float hr  = gh[j]         + b_hh[j];
    float hz  = gh[HSZ + j]   + b_hh[HSZ + j];
    float hn  = gh[2*HSZ + j] + b_hh[2*HSZ + j];
    float r = 1.f / (1.f + expf(-(ir + hr)));
    float z = 1.f / (1.f + expf(-(iz + hz)));
    float n = tanhf(in_ + r * hn);
    float h = (1.f - z) * n + z * h0[j];
    out[j]       = h;
    out[HSZ + j] = h;
}

extern "C" void kernel_launch(void* const* d_in, const int* in_sizes, int n_in,
                              void* d_out, int out_size, void* d_ws, size_t ws_size,
                              hipStream_t stream) {
    const float* data    = (const float*)d_in[0];
    const float* hidden  = (const float*)d_in[1];
    const float* fgat_W  = (const float*)d_in[2];
    const float* fgat_al = (const float*)d_in[3];
    // d_in[4] = fgat_ar (unused: er[0] = h[0]*ar = 0 since padded row 0 is zero)
    const float* fgat_b  = (const float*)d_in[5];
    const float* tgat_W  = (const float*)d_in[6];
    const float* tgat_al = (const float*)d_in[7];
    // d_in[8] = tgat_ar (unused, same reason)
    const float* tgat_b  = (const float*)d_in[9];
    const float* W_ih    = (const float*)d_in[10];
    const float* W_hh    = (const float*)d_in[11];
    const float* b_ih    = (const float*)d_in[12];
    const float* b_hh    = (const float*)d_in[13];
    float* ws  = (float*)d_ws;
    float* out = (float*)d_out;

    gat_matmul<<<32, 256, 0, stream>>>(data, fgat_W, tgat_W, ws);
    gat_softmax_assemble<<<1, 512, 0, stream>>>(data, fgat_al, fgat_b,
                                                tgat_al, tgat_b, ws);
    big_matvec<<<GI_NB + GH_NB, 256, 0, stream>>>(W_ih, W_hh, hidden, ws);
    gru_combine<<<(HSZ + 255) / 256, 256, 0, stream>>>(hidden, b_ih, b_hh, ws, out);
}

// Round 5
// 140.671 us; speedup vs baseline: 1.3643x; 1.1451x over previous
//
#include <hip/hip_runtime.h>

#define FEATS 64
#define HSZ   4096
#define ISZ   12480          // (FEATS+1)*FEATS*3
#define I4    (ISZ/4)        // 3120 float4
#define H4    (HSZ/4)        // 1024 float4

// workspace layout (float offsets)
#define X_OFF  0             // 12480
#define GI_OFF 12480         // 12288
#define GH_OFF 24768         // 12288

#define GI_RPW 4                      // rows per wave (GI)
#define GI_RPB 16                     // rows per block
#define GH_RPW 12                     // rows per wave (GH), 3 passes of 4
#define GH_RPB 48
#define GI_NB  (3 * HSZ / GI_RPB)     // 768
#define GH_NB  (3 * HSZ / GH_RPB)     // 256  -> total 1024 blocks = 4/CU, one pass

typedef float f4 __attribute__((ext_vector_type(4)));

// ---------------- A: fused GAT (2 blocks: 0=feat, 1=time) --------------------------
__global__ __launch_bounds__(256)
void gat_fused(const float* __restrict__ data,
               const float* __restrict__ fW, const float* __restrict__ fal,
               const float* __restrict__ fb,
               const float* __restrict__ tW, const float* __restrict__ tal,
               const float* __restrict__ tb,
               float* __restrict__ ws) {
    __shared__ float ld[64][65];   // (possibly transposed) input rows
    __shared__ float Wl[64][65];
    __shared__ float hb[64][65];
    __shared__ float out0[64];
    int w   = blockIdx.x;          // 0: feat GAT, 1: time GAT
    int tid = threadIdx.x;
    const float* W  = w ? tW  : fW;
    const float* al = w ? tal : fal;
    const float* bb = w ? tb  : fb;

    for (int i = tid; i < 4096; i += 256) {
        int r = i >> 6, c = i & 63;
        float v = data[i];
        if (w) ld[c][r] = v; else ld[r][c] = v;   // time GAT consumes data^T
        Wl[r][c] = W[i];
    }
    __syncthreads();

    // h = ld @ Wl. One wave per 16-row group: j = lane, broadcast ld reads.
    {
        int vbase = (tid >> 6) * 16;
        int j     = tid & 63;
        float acc[16];
        #pragma unroll
        for (int v = 0; v < 16; ++v) acc[v] = 0.f;
        for (int k = 0; k < 64; ++k) {
            float wk = Wl[k][j];
            #pragma unroll
            for (int v = 0; v < 16; ++v)
                acc[v] = fmaf(ld[vbase + v][k], wk, acc[v]);
        }
        #pragma unroll
        for (int v = 0; v < 16; ++v) hb[vbase + v][j] = acc[v];
    }
    __syncthreads();

    // softmax over the 65-node star, per head j. Node 0: h=0 -> e=0 (ar drops out).
    if (tid < 64) {
        int j = tid;
        float a = al[j];
        float m = 0.f;                     // includes node-0 term e=0
        for (int v = 0; v < 64; ++v) {
            float e = hb[v][j] * a;
            e = e > 0.f ? e : 0.2f * e;
            m = fmaxf(m, e);
        }
        float sum = __expf(0.f - m);       // node-0 term (zero numerator)
        float num = 0.f;
        for (int v = 0; v < 64; ++v) {
            float hv = hb[v][j];
            float e  = hv * a;
            e = e > 0.f ? e : 0.2f * e;
            float p  = __expf(e - m);
            sum += p;
            num += p * hv;
        }
        out0[j] = num / sum;
    }
    __syncthreads();

    // x[(n*64+f)*3 + c]: c0 = data_r (block 0), c1 = feat_r+fb, c2 = time_r+tb
    for (int i = tid; i < 4160; i += 256) {
        int n = i >> 6, f = i & 63;
        float val = ((n == 0) ? out0[f] : hb[n - 1][f]) + bb[f];
        ws[X_OFF + i * 3 + 1 + w] = val;
        if (w == 0)
            ws[X_OFF + i * 3] = (n == 0) ? 0.f : data[(n - 1) * 64 + f];
    }
}

// ---------------- B: the two big matvecs (memory-bound; 815 MB of weights) ---------
__device__ __forceinline__ float wave_reduce(float v) {
    #pragma unroll
    for (int off = 32; off > 0; off >>= 1) v += __shfl_down(v, off);
    return v;
}

__device__ __forceinline__ float fma4(f4 w, f4 v, float a) {
    return fmaf(w.x, v.x, fmaf(w.y, v.y, fmaf(w.z, v.z, fmaf(w.w, v.w, a))));
}

__device__ __forceinline__ f4 ntload(const f4* p) {
    return __builtin_nontemporal_load(p);   // weights are use-once: bypass L2 insert
}

__global__ __launch_bounds__(256, 4)
void big_matvec(const float* __restrict__ W_ih,
                const float* __restrict__ W_hh,
                const float* __restrict__ h0,
                float* __restrict__ ws) {
    int b    = blockIdx.x;
    int wave = threadIdx.x >> 6;
    int lane = threadIdx.x & 63;

    if (b < GI_NB) {
        // 4 rows per wave, 49.9 KB each; x re-read once per 4 rows (L2-resident)
        int r = b * GI_RPB + wave * GI_RPW;
        const f4* x4 = (const f4*)(ws + X_OFF);
        const f4* W0 = (const f4*)W_ih + (size_t)r * I4;
        const f4* W1 = W0 + I4;
        const f4* W2 = W1 + I4;
        const f4* W3 = W2 + I4;
        float a0 = 0.f, a1 = 0.f, a2 = 0.f, a3 = 0.f;
        int k = lane;
        #pragma unroll 4
        for (int i = 0; i < 48; ++i, k += 64) {
            f4 v = x4[k];
            a0 = fma4(ntload(W0 + k), v, a0);
            a1 = fma4(ntload(W1 + k), v, a1);
            a2 = fma4(ntload(W2 + k), v, a2);
            a3 = fma4(ntload(W3 + k), v, a3);
        }
        if (lane < 48) {                       // remainder: 3120 = 48*64 + 48
            int kk = 3072 + lane;
            f4 v = x4[kk];
            a0 = fma4(ntload(W0 + kk), v, a0);
            a1 = fma4(ntload(W1 + kk), v, a1);
            a2 = fma4(ntload(W2 + kk), v, a2);
            a3 = fma4(ntload(W3 + kk), v, a3);
        }
        a0 = wave_reduce(a0);
        a1 = wave_reduce(a1);
        a2 = wave_reduce(a2);
        a3 = wave_reduce(a3);
        if (lane == 0) {
            ws[GI_OFF + r]     = a0;
            ws[GI_OFF + r + 1] = a1;
            ws[GI_OFF + r + 2] = a2;
            ws[GI_OFF + r + 3] = a3;
        }
    } else {
        // 12 rows per wave in 3 passes of 4; h0 (16 KB) L2-resident
        int base = (b - GI_NB) * GH_RPB + wave * GH_RPW;
        const f4* h4 = (const f4*)h0;
        #pragma unroll
        for (int p = 0; p < GH_RPW; p += 4) {
            int r = base + p;
            const f4* W0 = (const f4*)W_hh + (size_t)r * H4;
            const f4* W1 = W0 + H4;
            const f4* W2 = W1 + H4;
            const f4* W3 = W2 + H4;
            float a0 = 0.f, a1 = 0.f, a2 = 0.f, a3 = 0.f;
            int k = lane;
            #pragma unroll 4
            for (int i = 0; i < 16; ++i, k += 64) {   // 1024 = 16*64 exactly
                f4 v = h4[k];
                a0 = fma4(ntload(W0 + k), v, a0);
                a1 = fma4(ntload(W1 + k), v, a1);
                a2 = fma4(ntload(W2 + k), v, a2);
                a3 = fma4(ntload(W3 + k), v, a3);
            }
            a0 = wave_reduce(a0);
            a1 = wave_reduce(a1);
            a2 = wave_reduce(a2);
            a3 = wave_reduce(a3);
            if (lane == 0) {
                ws[GH_OFF + r]     = a0;
                ws[GH_OFF + r + 1] = a1;
                ws[GH_OFF + r + 2] = a2;
                ws[GH_OFF + r + 3] = a3;
            }
        }
    }
}

// ---------------- C: GRU gate math + write both output copies ----------------------
__global__ void gru_combine(const float* __restrict__ h0,
                            const float* __restrict__ b_ih,
                            const float* __restrict__ b_hh,
                            const float* __restrict__ ws,
                            float* __restrict__ out) {
    int j = blockIdx.x * 256 + threadIdx.x;
    if (j >= HSZ) return;
    const float* gi = ws + GI_OFF;
    const float* gh = ws + GH_OFF;
    float ir  = gi[j]         + b_ih[j];
    float iz  = gi[HSZ + j]   + b_ih[HSZ + j];
    float in_ = gi[2*HSZ + j] + b_ih[2*HSZ + j];
    float hr  = gh[j]         + b_hh[j];
    float hz  = gh[HSZ + j]   + b_hh[HSZ + j];
    float hn  = gh[2*HSZ + j] + b_hh[2*HSZ + j];
    float r = 1.f / (1.f + expf(-(ir + hr)));
    float z = 1.f / (1.f + expf(-(iz + hz)));
    float n = tanhf(in_ + r * hn);
    float h = (1.f - z) * n + z * h0[j];
    out[j]       = h;
    out[HSZ + j] = h;
}

extern "C" void kernel_launch(void* const* d_in, const int* in_sizes, int n_in,
                              void* d_out, int out_size, void* d_ws, size_t ws_size,
                              hipStream_t stream) {
    const float* data    = (const float*)d_in[0];
    const float* hidden  = (const float*)d_in[1];
    const float* fgat_W  = (const float*)d_in[2];
    const float* fgat_al = (const float*)d_in[3];
    // d_in[4] = fgat_ar (unused: er[0] = h[0]*ar = 0 since padded row 0 is zero)
    const float* fgat_b  = (const float*)d_in[5];
    const float* tgat_W  = (const float*)d_in[6];
    const float* tgat_al = (const float*)d_in[7];
    // d_in[8] = tgat_ar (unused, same reason)
    const float* tgat_b  = (const float*)d_in[9];
    const float* W_ih    = (const float*)d_in[10];
    const float* W_hh    = (const float*)d_in[11];
    const float* b_ih    = (const float*)d_in[12];
    const float* b_hh    = (const float*)d_in[13];
    float* ws  = (float*)d_ws;
    float* out = (float*)d_out;

    gat_fused<<<2, 256, 0, stream>>>(data, fgat_W, fgat_al, fgat_b,
                                     tgat_W, tgat_al, tgat_b, ws);
    big_matvec<<<GI_NB + GH_NB, 256, 0, stream>>>(W_ih, W_hh, hidden, ws);
    gru_combine<<<HSZ / 256, 256, 0, stream>>>(hidden, b_ih, b_hh, ws, out);
}